// Round 7
// baseline (246.178 us; speedup 1.0000x reference)
//
#include <hip/hip_runtime.h>
#include <hip/hip_bf16.h>

#define BSZ 4
#define S1v 2048
#define S2v 2048
#define DM 512
#define NH 8
#define HD 64
#define SCALE 0.044194173824159216f
#define L2E 1.4426950408889634f
#define SC_L2E (0.044194173824159216f * 1.4426950408889634f)
#define CBIAS 0.0028152f   /* log2(1+2^-9): centers truncating bf16 pack */
#define NEGB (-1e30f)

typedef __bf16 bf16x8 __attribute__((ext_vector_type(8)));
typedef float f32x4 __attribute__((ext_vector_type(4)));

__device__ __forceinline__ unsigned short f2bf(float f) {
  union { float f; unsigned u; } v; v.f = f;
  unsigned r = v.u + 0x7FFFu + ((v.u >> 16) & 1u);
  return (unsigned short)(r >> 16);
}
__device__ __forceinline__ unsigned asu(float f) {
  union { float f; unsigned u; } v; v.f = f; return v.u;
}

// ------------- weight transpose + cast, both weights in one dispatch ----------
__global__ __launch_bounds__(256)
void wtrans2(const float* __restrict__ Wa, unsigned short* __restrict__ Wta,
             const float* __restrict__ Wb, unsigned short* __restrict__ Wtb) {
  const float* W = blockIdx.z ? Wb : Wa;
  unsigned short* Wt = blockIdx.z ? Wtb : Wta;
  __shared__ float tile[32][33];
  const int tx = threadIdx.x, ty = threadIdx.y;     // block (32,8)
  const int n0 = blockIdx.x * 32, k0 = blockIdx.y * 32;
#pragma unroll
  for (int i = 0; i < 32; i += 8)
    tile[ty + i][tx] = W[(size_t)(k0 + ty + i) * DM + n0 + tx];
  __syncthreads();
#pragma unroll
  for (int i = 0; i < 32; i += 8)
    Wt[(size_t)(n0 + ty + i) * DM + k0 + tx] = f2bf(tile[tx][ty + i]);
}

// ------------- projection GEMMs (Q and KV), register-prefetch pipelined -------
// z=0: Y0 = X0 @ W0 + b0 ; z=1: Y1 = X1 @ W1 + b1. 512 blocks = 2/CU.
__global__ __launch_bounds__(256, 2)
void proj_gemm(const float* __restrict__ X0, const unsigned short* __restrict__ Wt0,
               const float* __restrict__ bias0, unsigned short* __restrict__ Y0,
               const float* __restrict__ X1, const unsigned short* __restrict__ Wt1,
               const float* __restrict__ bias1, unsigned short* __restrict__ Y1) {
  const float* X = blockIdx.z ? X1 : X0;
  const unsigned short* Wt = blockIdx.z ? Wt1 : Wt0;
  const float* bias = blockIdx.z ? bias1 : bias0;
  unsigned short* Y = blockIdx.z ? Y1 : Y0;
  __shared__ unsigned short Xs[128][72];
  __shared__ unsigned short Ws[128][72];
  const int tid = threadIdx.x;
  const int wv = tid >> 6, lane = tid & 63;
  const int ln = lane & 15, qd = lane >> 4, q8 = qd * 8;
  const int wm = (wv >> 1) * 64, wn = (wv & 1) * 64;
  const int m0 = blockIdx.x * 128, n0 = blockIdx.y * 128;
  const int xr_r = tid >> 4, xr_c = (tid & 15) * 4;  // + i*16 rows
  const int wr_r = tid >> 3, wr_c = (tid & 7) * 8;   // + i*32 rows
  f32x4 acc[4][4] = {};
  float4 xr[8]; uint4 wr[4];
#pragma unroll
  for (int i = 0; i < 8; ++i)
    xr[i] = *(const float4*)(X + (size_t)(m0 + xr_r + i * 16) * DM + xr_c);
#pragma unroll
  for (int i = 0; i < 4; ++i)
    wr[i] = *(const uint4*)(Wt + (size_t)(n0 + wr_r + i * 32) * DM + wr_c);

  for (int k0 = 0; k0 < DM; k0 += 64) {
    __syncthreads();
#pragma unroll
    for (int i = 0; i < 8; ++i) {                   // regs -> LDS (cvt f32->bf16)
      ushort4 bv;
      bv.x = f2bf(xr[i].x); bv.y = f2bf(xr[i].y);
      bv.z = f2bf(xr[i].z); bv.w = f2bf(xr[i].w);
      *(ushort4*)&Xs[xr_r + i * 16][xr_c] = bv;
    }
#pragma unroll
    for (int i = 0; i < 4; ++i)
      *(uint4*)&Ws[wr_r + i * 32][wr_c] = wr[i];
    __syncthreads();
    if (k0 + 64 < DM) {                             // prefetch next K-tile
      const int kn = k0 + 64;
#pragma unroll
      for (int i = 0; i < 8; ++i)
        xr[i] = *(const float4*)(X + (size_t)(m0 + xr_r + i * 16) * DM + kn + xr_c);
#pragma unroll
      for (int i = 0; i < 4; ++i)
        wr[i] = *(const uint4*)(Wt + (size_t)(n0 + wr_r + i * 32) * DM + kn + wr_c);
    }
#pragma unroll
    for (int kk = 0; kk < 2; ++kk) {
      bf16x8 aF[4], bF[4];
#pragma unroll
      for (int i = 0; i < 4; ++i)
        aF[i] = *(const bf16x8*)&Xs[wm + 16 * i + ln][kk * 32 + q8];
#pragma unroll
      for (int j = 0; j < 4; ++j)
        bF[j] = *(const bf16x8*)&Ws[wn + 16 * j + ln][kk * 32 + q8];
#pragma unroll
      for (int i = 0; i < 4; ++i)
#pragma unroll
        for (int j = 0; j < 4; ++j)
          acc[i][j] = __builtin_amdgcn_mfma_f32_16x16x32_bf16(aF[i], bF[j], acc[i][j], 0, 0, 0);
    }
  }
#pragma unroll
  for (int i = 0; i < 4; ++i)
#pragma unroll
    for (int j = 0; j < 4; ++j) {
      const int n = n0 + wn + 16 * j + ln;
      const float bb = bias[n];
#pragma unroll
      for (int r = 0; r < 4; ++r) {
        const int m = m0 + wm + 16 * i + qd * 4 + r;
        Y[(size_t)m * DM + n] = f2bf(acc[i][j][r] + bb);
      }
    }
}

// ---------------- K^T builder with k-permutation baked in ----------------------
// Kt[(bh*64+d)][s_blk*128 + c'] = K[b][s_blk*128 + sigma(c')][h*64+d]
// sigma(c') = 16*(c'&7) + (c'>>3); matches flash's single-phase P pack.
__global__ __launch_bounds__(256)
void ktrans(const unsigned short* __restrict__ K, unsigned short* __restrict__ Kt) {
  __shared__ unsigned short T[128][72];
  const int tid = threadIdx.x;
  const int bh = blockIdx.y, b = bh >> 3, h8 = bh & 7;
  const int s0 = blockIdx.x * 128;
#pragma unroll
  for (int i = 0; i < 4; ++i) {                     // load tile [128 s][64 d]
    int cid = tid + i * 256;
    int r = cid >> 3, ch = (cid & 7) * 8;
    *(uint4*)&T[r][ch] =
        *(const uint4*)(K + (size_t)(b * S2v + s0 + r) * DM + h8 * HD + ch);
  }
  __syncthreads();
#pragma unroll
  for (int i = 0; i < 4; ++i) {                     // write [64 d][128 c']
    int cid = tid + i * 256;
    int d = cid >> 4, a = cid & 15;                 // c' = a*8 + e -> key 16e + a
    ushort4 v0, v1;
    v0.x = T[16 * 0 + a][d]; v0.y = T[16 * 1 + a][d];
    v0.z = T[16 * 2 + a][d]; v0.w = T[16 * 3 + a][d];
    v1.x = T[16 * 4 + a][d]; v1.y = T[16 * 5 + a][d];
    v1.z = T[16 * 6 + a][d]; v1.w = T[16 * 7 + a][d];
    unsigned short* o = Kt + ((size_t)(bh * HD + d)) * (size_t)S2v + s0 + a * 8;
    *(ushort4*)o = v0;
    *(ushort4*)(o + 4) = v1;
  }
}

// ---------------- flash attention (V = K), masked, static softmax --------------
// grid (S1/128, BSZ*NH), block 256: 4 waves x 32 Q-rows (2 subtiles of 16).
// Single-phase P pack (one lgkmcnt drain/iter), XOR-swizzled conflict-free LDS,
// register prefetch of next K/V/m2 staging -> global latency hidden by compute.
__global__ __launch_bounds__(256, 2)
void flash_attn(const unsigned short* __restrict__ Qb, const unsigned short* __restrict__ Kb,
                const unsigned short* __restrict__ Kt, const int* __restrict__ m1,
                const int* __restrict__ m2, float* __restrict__ attn) {
  __shared__ unsigned short Ks[128][64];            // swz: g^(r&7)
  __shared__ unsigned short Vts[64][128];           // swz: g^(r&15)
  __shared__ unsigned short Ps[4][32][128];         // swz: g^(row&15)
  __shared__ int m2s[128];

  const int tid = threadIdx.x;
  const int wv = tid >> 6, lane = tid & 63;
  const int ln = lane & 15, qd = lane >> 4, q8 = qd * 8;
  const int lnk7 = ln & 7;
  const int bh = blockIdx.y;
  const int b = bh >> 3, h = bh & 7;
  const int q0 = blockIdx.x * 128;

  // Q fragments straight from global (one-time, L2-warm from proj_gemm)
  bf16x8 aQ[2][2];
#pragma unroll
  for (int t = 0; t < 2; ++t) {
    const size_t rbase =
        ((size_t)(b * S1v + q0 + wv * 32 + t * 16 + ln)) * DM + h * HD;
    aQ[t][0] = *(const bf16x8*)(Qb + rbase + q8);
    aQ[t][1] = *(const bf16x8*)(Qb + rbase + 32 + q8);
  }

  float acoef[2][4];                                // 0 if m1==0 (uniform row)
#pragma unroll
  for (int t = 0; t < 2; ++t)
#pragma unroll
    for (int r = 0; r < 4; ++r)
      acoef[t][r] = (m1[b * S1v + q0 + wv * 32 + t * 16 + qd * 4 + r] == 0) ? 0.f : 1.f;

  // staging index helpers (swizzle keys constant across i: i*32%8==0, i*16%16==0)
  const int kr_r = tid >> 3, kr_g = tid & 7;        // K rows kr_r + i*32
  const int vr_r = tid >> 4, vr_g = tid & 15;       // V rows vr_r + i*16
  const int ks_g = (kr_g ^ (kr_r & 7)) * 8;
  const int vs_g = (vr_g ^ (vr_r & 15)) * 8;

  // prefetch iteration 0
  uint4 kr[4], vr[4];
#pragma unroll
  for (int i = 0; i < 4; ++i)
    kr[i] = *(const uint4*)(Kb + ((size_t)(b * S2v + kr_r + i * 32)) * DM + h * HD + kr_g * 8);
#pragma unroll
  for (int i = 0; i < 4; ++i)
    vr[i] = *(const uint4*)(Kt + ((size_t)(bh * HD + vr_r + i * 16)) * (size_t)S2v + vr_g * 8);
  int mreg = (tid < 128) ? m2[b * S2v + tid] : 0;

  float lrow[2][4] = {};
  f32x4 O[2][4] = {};

  for (int s0 = 0; s0 < S2v; s0 += 128) {
    __syncthreads();
#pragma unroll
    for (int i = 0; i < 4; ++i)
      *(uint4*)&Ks[kr_r + i * 32][ks_g] = kr[i];
#pragma unroll
    for (int i = 0; i < 4; ++i)
      *(uint4*)&Vts[vr_r + i * 16][vs_g] = vr[i];
    if (tid < 128) m2s[tid] = mreg;
    __syncthreads();

    if (s0 + 128 < S2v) {                           // prefetch next KV tile
      const int sn = s0 + 128;
#pragma unroll
      for (int i = 0; i < 4; ++i)
        kr[i] = *(const uint4*)(Kb + ((size_t)(b * S2v + sn + kr_r + i * 32)) * DM + h * HD + kr_g * 8);
#pragma unroll
      for (int i = 0; i < 4; ++i)
        vr[i] = *(const uint4*)(Kt + ((size_t)(bh * HD + vr_r + i * 16)) * (size_t)S2v + sn + vr_g * 8);
      if (tid < 128) mreg = m2[b * S2v + sn + tid];
    }

    // S = Q K^T : two 16-row subtiles share the K fragments
    f32x4 sc[2][8];
#pragma unroll
    for (int j = 0; j < 8; ++j) {
      const int row = 16 * j + ln;
      const bf16x8 b0 = *(const bf16x8*)&Ks[row][(qd ^ lnk7) * 8];
      const bf16x8 b1 = *(const bf16x8*)&Ks[row][((qd + 4) ^ lnk7) * 8];
#pragma unroll
      for (int t = 0; t < 2; ++t) {
        f32x4 z = {};
        z = __builtin_amdgcn_mfma_f32_16x16x32_bf16(aQ[t][0], b0, z, 0, 0, 0);
        sc[t][j] = __builtin_amdgcn_mfma_f32_16x16x32_bf16(aQ[t][1], b1, z, 0, 0, 0);
      }
    }

    float moff[8];
#pragma unroll
    for (int j = 0; j < 8; ++j)
      moff[j] = (m2s[16 * j + ln] != 0) ? 0.f : NEGB;

    // p = exp2( a * (sc*SC_L2E + moff) + CBIAS ); masked->0, uniform rows->2^CBIAS
#pragma unroll
    for (int t = 0; t < 2; ++t)
#pragma unroll
      for (int j = 0; j < 8; ++j)
#pragma unroll
        for (int r = 0; r < 4; ++r) {
          const float e = fmaf(acoef[t][r], fmaf(sc[t][j][r], SC_L2E, moff[j]), CBIAS);
          const float p = __builtin_amdgcn_exp2f(e);
          lrow[t][r] += p;
          sc[t][j][r] = p;
        }

    // single-phase pack: row q, cols c' = ln*8..ln*8+7 (one ds_write_b128 each)
#pragma unroll
    for (int t = 0; t < 2; ++t)
#pragma unroll
      for (int r = 0; r < 4; ++r) {
        uint4 dw;
        dw.x = __builtin_amdgcn_perm(asu(sc[t][1][r]), asu(sc[t][0][r]), 0x07060302u);
        dw.y = __builtin_amdgcn_perm(asu(sc[t][3][r]), asu(sc[t][2][r]), 0x07060302u);
        dw.z = __builtin_amdgcn_perm(asu(sc[t][5][r]), asu(sc[t][4][r]), 0x07060302u);
        dw.w = __builtin_amdgcn_perm(asu(sc[t][7][r]), asu(sc[t][6][r]), 0x07060302u);
        const int rw = qd * 4 + r;                  // row&15 (t*16 drops out)
        *(uint4*)&Ps[wv][t * 16 + rw][(ln ^ rw) * 8] = dw;
      }
    __asm__ volatile("s_waitcnt lgkmcnt(0)" ::: "memory");  // pack visible (wave-private)

    // O += P V : subtiles share the V fragments
#pragma unroll
    for (int kk = 0; kk < 4; ++kk) {
      const int pg = ((4 * kk + qd) ^ ln) * 8;
      const bf16x8 aP0 = *(const bf16x8*)&Ps[wv][ln][pg];
      const bf16x8 aP1 = *(const bf16x8*)&Ps[wv][16 + ln][pg];
#pragma unroll
      for (int jn = 0; jn < 4; ++jn) {
        const bf16x8 bV = *(const bf16x8*)&Vts[16 * jn + ln][pg];
        O[0][jn] = __builtin_amdgcn_mfma_f32_16x16x32_bf16(aP0, bV, O[0][jn], 0, 0, 0);
        O[1][jn] = __builtin_amdgcn_mfma_f32_16x16x32_bf16(aP1, bV, O[1][jn], 0, 0, 0);
      }
    }
  }

#pragma unroll
  for (int t = 0; t < 2; ++t)
#pragma unroll
    for (int r = 0; r < 4; ++r) {
      float l = lrow[t][r];
#pragma unroll
      for (int msk = 1; msk < 16; msk <<= 1) l += __shfl_xor(l, msk, 64);
      const float inv = l > 0.f ? 1.0f / l : 0.f;
      const int m = q0 + wv * 32 + t * 16 + qd * 4 + r;
#pragma unroll
      for (int jn = 0; jn < 4; ++jn)
        attn[((size_t)(b * S1v + m)) * DM + h * HD + 16 * jn + ln] = O[t][jn][r] * inv;
    }
}

// -------- fused LN2(attn + LN1(attn + modal1)) : wave-per-row, no LDS ---------
__global__ __launch_bounds__(256)
void ln_fused(const float* __restrict__ attn, const float* __restrict__ modal1,
              const float* __restrict__ g1, const float* __restrict__ b1,
              const float* __restrict__ g2, const float* __restrict__ b2,
              float* __restrict__ out) {
  const int wv = threadIdx.x >> 6, lane = threadIdx.x & 63;
  const int row = blockIdx.x * 4 + wv;
  const int c = lane * 8;                           // 8 floats per lane
  const size_t base = (size_t)row * DM + c;
  const float4 a0 = *(const float4*)(attn + base);
  const float4 a1 = *(const float4*)(attn + base + 4);
  const float4 mo0 = *(const float4*)(modal1 + base);
  const float4 mo1 = *(const float4*)(modal1 + base + 4);
  float av[8] = { a0.x, a0.y, a0.z, a0.w, a1.x, a1.y, a1.z, a1.w };
  float mv[8] = { mo0.x, mo0.y, mo0.z, mo0.w, mo1.x, mo1.y, mo1.z, mo1.w };
  float x[8];
  float s = 0.f, q = 0.f;
#pragma unroll
  for (int i = 0; i < 8; ++i) {
    x[i] = av[i] + mv[i];
    s += x[i]; q += x[i] * x[i];
  }
#pragma unroll
  for (int m = 1; m < 64; m <<= 1) { s += __shfl_xor(s, m, 64); q += __shfl_xor(q, m, 64); }
  const float mu = s * (1.0f / DM);
  const float rinv = rsqrtf(q * (1.0f / DM) - mu * mu + 1e-5f);
  const float4 G10 = *(const float4*)(g1 + c), G11 = *(const float4*)(g1 + c + 4);
  const float4 B10 = *(const float4*)(b1 + c), B11 = *(const float4*)(b1 + c + 4);
  const float gg1[8] = { G10.x, G10.y, G10.z, G10.w, G11.x, G11.y, G11.z, G11.w };
  const float bb1[8] = { B10.x, B10.y, B10.z, B10.w, B11.x, B11.y, B11.z, B11.w };
  float y[8];
  float s2 = 0.f, q2 = 0.f;
#pragma unroll
  for (int i = 0; i < 8; ++i) {
    y[i] = av[i] + (x[i] - mu) * rinv * gg1[i] + bb1[i];
    s2 += y[i]; q2 += y[i] * y[i];
  }
#pragma unroll
  for (int m = 1; m < 64; m <<= 1) { s2 += __shfl_xor(s2, m, 64); q2 += __shfl_xor(q2, m, 64); }
  const float mu2 = s2 * (1.0f / DM);
  const float rinv2 = rsqrtf(q2 * (1.0f / DM) - mu2 * mu2 + 1e-5f);
  const float4 G20 = *(const float4*)(g2 + c), G21 = *(const float4*)(g2 + c + 4);
  const float4 B20 = *(const float4*)(b2 + c), B21 = *(const float4*)(b2 + c + 4);
  const float gg2[8] = { G20.x, G20.y, G20.z, G20.w, G21.x, G21.y, G21.z, G21.w };
  const float bb2[8] = { B20.x, B20.y, B20.z, B20.w, B21.x, B21.y, B21.z, B21.w };
  float4 o0, o1;
  o0.x = (y[0] - mu2) * rinv2 * gg2[0] + bb2[0];
  o0.y = (y[1] - mu2) * rinv2 * gg2[1] + bb2[1];
  o0.z = (y[2] - mu2) * rinv2 * gg2[2] + bb2[2];
  o0.w = (y[3] - mu2) * rinv2 * gg2[3] + bb2[3];
  o1.x = (y[4] - mu2) * rinv2 * gg2[4] + bb2[4];
  o1.y = (y[5] - mu2) * rinv2 * gg2[5] + bb2[5];
  o1.z = (y[6] - mu2) * rinv2 * gg2[6] + bb2[6];
  o1.w = (y[7] - mu2) * rinv2 * gg2[7] + bb2[7];
  *(float4*)(out + base) = o0;
  *(float4*)(out + base + 4) = o1;
}

extern "C" void kernel_launch(void* const* d_in, const int* in_sizes, int n_in,
                              void* d_out, int out_size, void* d_ws, size_t ws_size,
                              hipStream_t stream) {
  const float* modal1 = (const float*)d_in[0];
  const float* modal2 = (const float*)d_in[1];
  const int*   m1     = (const int*)d_in[2];
  const int*   m2     = (const int*)d_in[3];
  const float* Wq     = (const float*)d_in[4];
  const float* bq     = (const float*)d_in[5];
  const float* Wkv    = (const float*)d_in[6];
  const float* bkv    = (const float*)d_in[7];
  const float* g1     = (const float*)d_in[8];
  const float* b1     = (const float*)d_in[9];
  // d_in[10..13] = FFN weights -> output discarded by the reference; skipped.
  const float* g2     = (const float*)d_in[14];
  const float* b2     = (const float*)d_in[15];
  float* out = (float*)d_out;

  char* ws = (char*)d_ws;
  unsigned short* q_bf  = (unsigned short*)(ws);                 //  8 MB
  unsigned short* k_bf  = (unsigned short*)(ws + 8388608);       //  8 MB
  unsigned short* kt_bf = (unsigned short*)(ws + 16777216);      //  8 MB
  unsigned short* wqt   = (unsigned short*)(ws + 25165824);      // 512 KB
  unsigned short* wkt   = (unsigned short*)(ws + 25690112);      // 512 KB
  float*          attn  = (float*)(ws + 26214400);               // 16 MB

  wtrans2<<<dim3(16, 16, 2), dim3(32, 8), 0, stream>>>(Wq, wqt, Wkv, wkt);
  proj_gemm<<<dim3(64, 4, 2), 256, 0, stream>>>(modal1, wqt, bq, q_bf,
                                                modal2, wkt, bkv, k_bf);
  ktrans<<<dim3(16, 32), 256, 0, stream>>>(k_bf, kt_bf);
  flash_attn<<<dim3(16, 32), 256, 0, stream>>>(q_bf, k_bf, kt_bf, m1, m2, attn);
  ln_fused<<<dim3(2048), 256, 0, stream>>>(attn, modal1, g1, b1, g2, b2, out);
}

// Round 8
// 206.373 us; speedup vs baseline: 1.1929x; 1.1929x over previous
//
#include <hip/hip_runtime.h>
#include <hip/hip_bf16.h>

#define BSZ 4
#define S1v 2048
#define S2v 2048
#define DM 512
#define NH 8
#define HD 64
#define SCALE 0.044194173824159216f
#define L2E 1.4426950408889634f
#define SC_L2E (0.044194173824159216f * 1.4426950408889634f)
#define CBIAS 0.0028152f   /* log2(1+2^-9): centers truncating bf16 pack */
#define NEGB (-1e30f)

typedef __bf16 bf16x8 __attribute__((ext_vector_type(8)));
typedef float f32x4 __attribute__((ext_vector_type(4)));

__device__ __forceinline__ unsigned short f2bf(float f) {
  union { float f; unsigned u; } v; v.f = f;
  unsigned r = v.u + 0x7FFFu + ((v.u >> 16) & 1u);
  return (unsigned short)(r >> 16);
}
__device__ __forceinline__ unsigned asu(float f) {
  union { float f; unsigned u; } v; v.f = f; return v.u;
}

// ------------- weight transpose + cast, both weights in one dispatch ----------
__global__ __launch_bounds__(256)
void wtrans2(const float* __restrict__ Wa, unsigned short* __restrict__ Wta,
             const float* __restrict__ Wb, unsigned short* __restrict__ Wtb) {
  const float* W = blockIdx.z ? Wb : Wa;
  unsigned short* Wt = blockIdx.z ? Wtb : Wta;
  __shared__ float tile[32][33];
  const int tx = threadIdx.x, ty = threadIdx.y;     // block (32,8)
  const int n0 = blockIdx.x * 32, k0 = blockIdx.y * 32;
#pragma unroll
  for (int i = 0; i < 32; i += 8)
    tile[ty + i][tx] = W[(size_t)(k0 + ty + i) * DM + n0 + tx];
  __syncthreads();
#pragma unroll
  for (int i = 0; i < 32; i += 8)
    Wt[(size_t)(n0 + ty + i) * DM + k0 + tx] = f2bf(tile[tx][ty + i]);
}

// ------------- projection GEMMs (Q and KV), register-prefetch pipelined -------
// z=0: Y0 = X0 @ W0 + b0 ; z=1: Y1 = X1 @ W1 + b1. 512 blocks = 2/CU.
__global__ __launch_bounds__(256, 2)
void proj_gemm(const float* __restrict__ X0, const unsigned short* __restrict__ Wt0,
               const float* __restrict__ bias0, unsigned short* __restrict__ Y0,
               const float* __restrict__ X1, const unsigned short* __restrict__ Wt1,
               const float* __restrict__ bias1, unsigned short* __restrict__ Y1) {
  const float* X = blockIdx.z ? X1 : X0;
  const unsigned short* Wt = blockIdx.z ? Wt1 : Wt0;
  const float* bias = blockIdx.z ? bias1 : bias0;
  unsigned short* Y = blockIdx.z ? Y1 : Y0;
  __shared__ unsigned short Xs[128][72];
  __shared__ unsigned short Ws[128][72];
  const int tid = threadIdx.x;
  const int wv = tid >> 6, lane = tid & 63;
  const int ln = lane & 15, qd = lane >> 4, q8 = qd * 8;
  const int wm = (wv >> 1) * 64, wn = (wv & 1) * 64;
  const int m0 = blockIdx.x * 128, n0 = blockIdx.y * 128;
  const int xr_r = tid >> 4, xr_c = (tid & 15) * 4;  // + i*16 rows
  const int wr_r = tid >> 3, wr_c = (tid & 7) * 8;   // + i*32 rows
  f32x4 acc[4][4] = {};
  float4 xr[8]; uint4 wr[4];
#pragma unroll
  for (int i = 0; i < 8; ++i)
    xr[i] = *(const float4*)(X + (size_t)(m0 + xr_r + i * 16) * DM + xr_c);
#pragma unroll
  for (int i = 0; i < 4; ++i)
    wr[i] = *(const uint4*)(Wt + (size_t)(n0 + wr_r + i * 32) * DM + wr_c);

  for (int k0 = 0; k0 < DM; k0 += 64) {
    __syncthreads();
#pragma unroll
    for (int i = 0; i < 8; ++i) {                   // regs -> LDS (cvt f32->bf16)
      ushort4 bv;
      bv.x = f2bf(xr[i].x); bv.y = f2bf(xr[i].y);
      bv.z = f2bf(xr[i].z); bv.w = f2bf(xr[i].w);
      *(ushort4*)&Xs[xr_r + i * 16][xr_c] = bv;
    }
#pragma unroll
    for (int i = 0; i < 4; ++i)
      *(uint4*)&Ws[wr_r + i * 32][wr_c] = wr[i];
    __syncthreads();
    if (k0 + 64 < DM) {                             // prefetch next K-tile
      const int kn = k0 + 64;
#pragma unroll
      for (int i = 0; i < 8; ++i)
        xr[i] = *(const float4*)(X + (size_t)(m0 + xr_r + i * 16) * DM + kn + xr_c);
#pragma unroll
      for (int i = 0; i < 4; ++i)
        wr[i] = *(const uint4*)(Wt + (size_t)(n0 + wr_r + i * 32) * DM + kn + wr_c);
    }
#pragma unroll
    for (int kk = 0; kk < 2; ++kk) {
      bf16x8 aF[4], bF[4];
#pragma unroll
      for (int i = 0; i < 4; ++i)
        aF[i] = *(const bf16x8*)&Xs[wm + 16 * i + ln][kk * 32 + q8];
#pragma unroll
      for (int j = 0; j < 4; ++j)
        bF[j] = *(const bf16x8*)&Ws[wn + 16 * j + ln][kk * 32 + q8];
#pragma unroll
      for (int i = 0; i < 4; ++i)
#pragma unroll
        for (int j = 0; j < 4; ++j)
          acc[i][j] = __builtin_amdgcn_mfma_f32_16x16x32_bf16(aF[i], bF[j], acc[i][j], 0, 0, 0);
    }
  }
#pragma unroll
  for (int i = 0; i < 4; ++i)
#pragma unroll
    for (int j = 0; j < 4; ++j) {
      const int n = n0 + wn + 16 * j + ln;
      const float bb = bias[n];
#pragma unroll
      for (int r = 0; r < 4; ++r) {
        const int m = m0 + wm + 16 * i + qd * 4 + r;
        Y[(size_t)m * DM + n] = f2bf(acc[i][j][r] + bb);
      }
    }
}

// ---------------- K^T builder with k-permutation baked in ----------------------
// Kt[(bh*64+d)][s_blk*128 + c'] = K[b][s_blk*128 + sigma(c')][h*64+d]
// sigma(c') = 16*(c'&7) + (c'>>3). LDS held transposed [d][s] (stride 130 ->
// odd dword stride): writes <=2-way, reads conflict-free lane-contiguous.
__global__ __launch_bounds__(256)
void ktrans(const unsigned short* __restrict__ K, unsigned short* __restrict__ Kt) {
  __shared__ unsigned short T2[64][130];
  const int tid = threadIdx.x;
  const int bh = blockIdx.y, b = bh >> 3, h8 = bh & 7;
  const int s0 = blockIdx.x * 128;
#pragma unroll
  for (int i = 0; i < 4; ++i) {                     // load [s][d], store T2[d][s]
    int cid = tid + i * 256;
    int r = cid >> 3, ch = (cid & 7) * 8;
    const uint4 v = *(const uint4*)(K + (size_t)(b * S2v + s0 + r) * DM + h8 * HD + ch);
    const ushort4 lo = *(const ushort4*)&v.x, hi = *(const ushort4*)&v.z;
    T2[ch + 0][r] = lo.x; T2[ch + 1][r] = lo.y;
    T2[ch + 2][r] = lo.z; T2[ch + 3][r] = lo.w;
    T2[ch + 4][r] = hi.x; T2[ch + 5][r] = hi.y;
    T2[ch + 6][r] = hi.z; T2[ch + 7][r] = hi.w;
  }
  __syncthreads();
#pragma unroll
  for (int i = 0; i < 4; ++i) {                     // emit [d][c'], c' = a*8+e
    int cid = tid + i * 256;
    int d = cid >> 4, a = cid & 15;
    ushort4 v0, v1;
    v0.x = T2[d][16 * 0 + a]; v0.y = T2[d][16 * 1 + a];
    v0.z = T2[d][16 * 2 + a]; v0.w = T2[d][16 * 3 + a];
    v1.x = T2[d][16 * 4 + a]; v1.y = T2[d][16 * 5 + a];
    v1.z = T2[d][16 * 6 + a]; v1.w = T2[d][16 * 7 + a];
    unsigned short* o = Kt + ((size_t)(bh * HD + d)) * (size_t)S2v + s0 + a * 8;
    *(ushort4*)o = v0;
    *(ushort4*)(o + 4) = v1;
  }
}

// ---------------- flash attention (V = K), masked, static softmax --------------
// grid (S1/128, BSZ*NH), block 256: 4 waves x 32 Q-rows (2 subtiles of 16).
// Single-phase P pack (one lgkmcnt drain/iter), XOR-swizzled conflict-free LDS.
// NO register prefetch of staging (R7's spill: 208 MB scratch traffic).
__global__ __launch_bounds__(256, 2)
void flash_attn(const unsigned short* __restrict__ Qb, const unsigned short* __restrict__ Kb,
                const unsigned short* __restrict__ Kt, const int* __restrict__ m1,
                const int* __restrict__ m2, float* __restrict__ attn) {
  __shared__ unsigned short Ks[128][64];            // swz: g^(r&7)
  __shared__ unsigned short Vts[64][128];           // swz: g^(r&15)
  __shared__ unsigned short Ps[4][32][128];         // swz: g^(row&15)
  __shared__ int m2s[128];

  const int tid = threadIdx.x;
  const int wv = tid >> 6, lane = tid & 63;
  const int ln = lane & 15, qd = lane >> 4, q8 = qd * 8;
  const int lnk7 = ln & 7;
  const int bh = blockIdx.y;
  const int b = bh >> 3, h = bh & 7;
  const int q0 = blockIdx.x * 128;

  // Q fragments straight from global (one-time, L2-warm from proj_gemm)
  bf16x8 aQ[2][2];
#pragma unroll
  for (int t = 0; t < 2; ++t) {
    const size_t rbase =
        ((size_t)(b * S1v + q0 + wv * 32 + t * 16 + ln)) * DM + h * HD;
    aQ[t][0] = *(const bf16x8*)(Qb + rbase + q8);
    aQ[t][1] = *(const bf16x8*)(Qb + rbase + 32 + q8);
  }

  float acoef[2][4];                                // 0 if m1==0 (uniform row)
#pragma unroll
  for (int t = 0; t < 2; ++t)
#pragma unroll
    for (int r = 0; r < 4; ++r)
      acoef[t][r] = (m1[b * S1v + q0 + wv * 32 + t * 16 + qd * 4 + r] == 0) ? 0.f : 1.f;

  // staging index helpers (swizzle keys constant across i: i*32%8==0, i*16%16==0)
  const int kr_r = tid >> 3, kr_g = tid & 7;        // K rows kr_r + i*32
  const int vr_r = tid >> 4, vr_g = tid & 15;       // V rows vr_r + i*16
  const int ks_g = (kr_g ^ (kr_r & 7)) * 8;
  const int vs_g = (vr_g ^ (vr_r & 15)) * 8;

  float lrow[2][4] = {};
  f32x4 O[2][4] = {};

  for (int s0 = 0; s0 < S2v; s0 += 128) {
    __syncthreads();
#pragma unroll
    for (int i = 0; i < 4; ++i)                     // K tile 128x64 (swizzled)
      *(uint4*)&Ks[kr_r + i * 32][ks_g] =
          *(const uint4*)(Kb + ((size_t)(b * S2v + s0 + kr_r + i * 32)) * DM + h * HD + kr_g * 8);
#pragma unroll
    for (int i = 0; i < 4; ++i)                     // V^T tile 64x128 (swizzled)
      *(uint4*)&Vts[vr_r + i * 16][vs_g] =
          *(const uint4*)(Kt + ((size_t)(bh * HD + vr_r + i * 16)) * (size_t)S2v + s0 + vr_g * 8);
    if (tid < 128) m2s[tid] = m2[b * S2v + s0 + tid];
    __syncthreads();

    // S = Q K^T : two 16-row subtiles share the K fragments
    f32x4 sc[2][8];
#pragma unroll
    for (int j = 0; j < 8; ++j) {
      const int row = 16 * j + ln;
      const bf16x8 b0 = *(const bf16x8*)&Ks[row][(qd ^ lnk7) * 8];
      const bf16x8 b1 = *(const bf16x8*)&Ks[row][((qd + 4) ^ lnk7) * 8];
#pragma unroll
      for (int t = 0; t < 2; ++t) {
        f32x4 z = {};
        z = __builtin_amdgcn_mfma_f32_16x16x32_bf16(aQ[t][0], b0, z, 0, 0, 0);
        sc[t][j] = __builtin_amdgcn_mfma_f32_16x16x32_bf16(aQ[t][1], b1, z, 0, 0, 0);
      }
    }

    float moff[8];
#pragma unroll
    for (int j = 0; j < 8; ++j)
      moff[j] = (m2s[16 * j + ln] != 0) ? 0.f : NEGB;

    // p = exp2( a * (sc*SC_L2E + moff) + CBIAS ); masked->0, uniform rows->2^CBIAS
#pragma unroll
    for (int t = 0; t < 2; ++t)
#pragma unroll
      for (int j = 0; j < 8; ++j)
#pragma unroll
        for (int r = 0; r < 4; ++r) {
          const float e = fmaf(acoef[t][r], fmaf(sc[t][j][r], SC_L2E, moff[j]), CBIAS);
          const float p = __builtin_amdgcn_exp2f(e);
          lrow[t][r] += p;
          sc[t][j][r] = p;
        }

    // single-phase pack: row q, cols c' = ln*8..ln*8+7 (one ds_write_b128 each)
#pragma unroll
    for (int t = 0; t < 2; ++t)
#pragma unroll
      for (int r = 0; r < 4; ++r) {
        uint4 dw;
        dw.x = __builtin_amdgcn_perm(asu(sc[t][1][r]), asu(sc[t][0][r]), 0x07060302u);
        dw.y = __builtin_amdgcn_perm(asu(sc[t][3][r]), asu(sc[t][2][r]), 0x07060302u);
        dw.z = __builtin_amdgcn_perm(asu(sc[t][5][r]), asu(sc[t][4][r]), 0x07060302u);
        dw.w = __builtin_amdgcn_perm(asu(sc[t][7][r]), asu(sc[t][6][r]), 0x07060302u);
        const int rw = qd * 4 + r;                  // row&15 (t*16 drops out)
        *(uint4*)&Ps[wv][t * 16 + rw][(ln ^ rw) * 8] = dw;
      }
    __asm__ volatile("s_waitcnt lgkmcnt(0)" ::: "memory");  // pack visible (wave-private)

    // O += P V : subtiles share the V fragments
#pragma unroll
    for (int kk = 0; kk < 4; ++kk) {
      const int pg = ((4 * kk + qd) ^ ln) * 8;
      const bf16x8 aP0 = *(const bf16x8*)&Ps[wv][ln][pg];
      const bf16x8 aP1 = *(const bf16x8*)&Ps[wv][16 + ln][pg];
#pragma unroll
      for (int jn = 0; jn < 4; ++jn) {
        const bf16x8 bV = *(const bf16x8*)&Vts[16 * jn + ln][pg];
        O[0][jn] = __builtin_amdgcn_mfma_f32_16x16x32_bf16(aP0, bV, O[0][jn], 0, 0, 0);
        O[1][jn] = __builtin_amdgcn_mfma_f32_16x16x32_bf16(aP1, bV, O[1][jn], 0, 0, 0);
      }
    }
  }

#pragma unroll
  for (int t = 0; t < 2; ++t)
#pragma unroll
    for (int r = 0; r < 4; ++r) {
      float l = lrow[t][r];
#pragma unroll
      for (int msk = 1; msk < 16; msk <<= 1) l += __shfl_xor(l, msk, 64);
      const float inv = l > 0.f ? 1.0f / l : 0.f;
      const int m = q0 + wv * 32 + t * 16 + qd * 4 + r;
#pragma unroll
      for (int jn = 0; jn < 4; ++jn)
        attn[((size_t)(b * S1v + m)) * DM + h * HD + 16 * jn + ln] = O[t][jn][r] * inv;
    }
}

// -------- fused LN2(attn + LN1(attn + modal1)) : wave-per-row, no LDS ---------
__global__ __launch_bounds__(256)
void ln_fused(const float* __restrict__ attn, const float* __restrict__ modal1,
              const float* __restrict__ g1, const float* __restrict__ b1,
              const float* __restrict__ g2, const float* __restrict__ b2,
              float* __restrict__ out) {
  const int wv = threadIdx.x >> 6, lane = threadIdx.x & 63;
  const int row = blockIdx.x * 4 + wv;
  const int c = lane * 8;                           // 8 floats per lane
  const size_t base = (size_t)row * DM + c;
  const float4 a0 = *(const float4*)(attn + base);
  const float4 a1 = *(const float4*)(attn + base + 4);
  const float4 mo0 = *(const float4*)(modal1 + base);
  const float4 mo1 = *(const float4*)(modal1 + base + 4);
  float av[8] = { a0.x, a0.y, a0.z, a0.w, a1.x, a1.y, a1.z, a1.w };
  float mv[8] = { mo0.x, mo0.y, mo0.z, mo0.w, mo1.x, mo1.y, mo1.z, mo1.w };
  float x[8];
  float s = 0.f, q = 0.f;
#pragma unroll
  for (int i = 0; i < 8; ++i) {
    x[i] = av[i] + mv[i];
    s += x[i]; q += x[i] * x[i];
  }
#pragma unroll
  for (int m = 1; m < 64; m <<= 1) { s += __shfl_xor(s, m, 64); q += __shfl_xor(q, m, 64); }
  const float mu = s * (1.0f / DM);
  const float rinv = rsqrtf(q * (1.0f / DM) - mu * mu + 1e-5f);
  const float4 G10 = *(const float4*)(g1 + c), G11 = *(const float4*)(g1 + c + 4);
  const float4 B10 = *(const float4*)(b1 + c), B11 = *(const float4*)(b1 + c + 4);
  const float gg1[8] = { G10.x, G10.y, G10.z, G10.w, G11.x, G11.y, G11.z, G11.w };
  const float bb1[8] = { B10.x, B10.y, B10.z, B10.w, B11.x, B11.y, B11.z, B11.w };
  float y[8];
  float s2 = 0.f, q2 = 0.f;
#pragma unroll
  for (int i = 0; i < 8; ++i) {
    y[i] = av[i] + (x[i] - mu) * rinv * gg1[i] + bb1[i];
    s2 += y[i]; q2 += y[i] * y[i];
  }
#pragma unroll
  for (int m = 1; m < 64; m <<= 1) { s2 += __shfl_xor(s2, m, 64); q2 += __shfl_xor(q2, m, 64); }
  const float mu2 = s2 * (1.0f / DM);
  const float rinv2 = rsqrtf(q2 * (1.0f / DM) - mu2 * mu2 + 1e-5f);
  const float4 G20 = *(const float4*)(g2 + c), G21 = *(const float4*)(g2 + c + 4);
  const float4 B20 = *(const float4*)(b2 + c), B21 = *(const float4*)(b2 + c + 4);
  const float gg2[8] = { G20.x, G20.y, G20.z, G20.w, G21.x, G21.y, G21.z, G21.w };
  const float bb2[8] = { B20.x, B20.y, B20.z, B20.w, B21.x, B21.y, B21.z, B21.w };
  float4 o0, o1;
  o0.x = (y[0] - mu2) * rinv2 * gg2[0] + bb2[0];
  o0.y = (y[1] - mu2) * rinv2 * gg2[1] + bb2[1];
  o0.z = (y[2] - mu2) * rinv2 * gg2[2] + bb2[2];
  o0.w = (y[3] - mu2) * rinv2 * gg2[3] + bb2[3];
  o1.x = (y[4] - mu2) * rinv2 * gg2[4] + bb2[4];
  o1.y = (y[5] - mu2) * rinv2 * gg2[5] + bb2[5];
  o1.z = (y[6] - mu2) * rinv2 * gg2[6] + bb2[6];
  o1.w = (y[7] - mu2) * rinv2 * gg2[7] + bb2[7];
  *(float4*)(out + base) = o0;
  *(float4*)(out + base + 4) = o1;
}

extern "C" void kernel_launch(void* const* d_in, const int* in_sizes, int n_in,
                              void* d_out, int out_size, void* d_ws, size_t ws_size,
                              hipStream_t stream) {
  const float* modal1 = (const float*)d_in[0];
  const float* modal2 = (const float*)d_in[1];
  const int*   m1     = (const int*)d_in[2];
  const int*   m2     = (const int*)d_in[3];
  const float* Wq     = (const float*)d_in[4];
  const float* bq     = (const float*)d_in[5];
  const float* Wkv    = (const float*)d_in[6];
  const float* bkv    = (const float*)d_in[7];
  const float* g1     = (const float*)d_in[8];
  const float* b1     = (const float*)d_in[9];
  // d_in[10..13] = FFN weights -> output discarded by the reference; skipped.
  const float* g2     = (const float*)d_in[14];
  const float* b2     = (const float*)d_in[15];
  float* out = (float*)d_out;

  char* ws = (char*)d_ws;
  unsigned short* q_bf  = (unsigned short*)(ws);                 //  8 MB
  unsigned short* k_bf  = (unsigned short*)(ws + 8388608);       //  8 MB
  unsigned short* kt_bf = (unsigned short*)(ws + 16777216);      //  8 MB
  unsigned short* wqt   = (unsigned short*)(ws + 25165824);      // 512 KB
  unsigned short* wkt   = (unsigned short*)(ws + 25690112);      // 512 KB
  float*          attn  = (float*)(ws + 26214400);               // 16 MB

  wtrans2<<<dim3(16, 16, 2), dim3(32, 8), 0, stream>>>(Wq, wqt, Wkv, wkt);
  proj_gemm<<<dim3(64, 4, 2), 256, 0, stream>>>(modal1, wqt, bq, q_bf,
                                                modal2, wkt, bkv, k_bf);
  ktrans<<<dim3(16, 32), 256, 0, stream>>>(k_bf, kt_bf);
  flash_attn<<<dim3(16, 32), 256, 0, stream>>>(q_bf, k_bf, kt_bf, m1, m2, attn);
  ln_fused<<<dim3(2048), 256, 0, stream>>>(attn, modal1, g1, b1, g2, b2, out);
}